// Round 2
// baseline (7068.611 us; speedup 1.0000x reference)
//
#include <hip/hip_runtime.h>
#include <math.h>

#pragma clang fp contract(off)

static constexpr int BATCH = 16;
static constexpr int NPTS0 = 2048;
static constexpr int KNN = 24;

// ---------------- workspace layout (bytes) ----------------
static constexpr size_t OFF_STATS = 0;                         // 4 stages * 4 doubles
static constexpr size_t OFF_BN    = 256;                       // (128+256+512+1024)*2 doubles
static constexpr size_t OFF_DE    = 32768;                     // 333 floats (dim_embed tables)
static constexpr size_t OFF_MAP   = 36864;                     // 1984 ints (out_idx tables)
static constexpr size_t OFF_XYZ1  = 49152;                                      // 16*1024*3 f32
static constexpr size_t OFF_XYZ2  = OFF_XYZ1 + (size_t)16*1024*3*4;
static constexpr size_t OFF_XYZ3  = OFF_XYZ2 + (size_t)16*512*3*4;
static constexpr size_t OFF_XYZ4  = OFF_XYZ3 + (size_t)16*256*3*4;
static constexpr size_t OFF_FPS0  = OFF_XYZ4 + (size_t)16*128*3*4;
static constexpr size_t OFF_FPS1  = OFF_FPS0 + (size_t)16*1024*4;
static constexpr size_t OFF_FPS2  = OFF_FPS1 + (size_t)16*512*4;
static constexpr size_t OFF_FPS3  = OFF_FPS2 + (size_t)16*256*4;
static constexpr size_t OFF_KNN   = OFF_FPS3 + (size_t)16*128*4;                // 16*1024*24 ints
static constexpr size_t OFF_FEATA = OFF_KNN + (size_t)16*1024*24*4;
static constexpr size_t OFF_FEATB = OFF_FEATA + (size_t)16*2048*64*4;
static constexpr size_t OFF_FEATS = OFF_FEATB + (size_t)16*2048*64*4;
static constexpr size_t OFF_AGG   = OFF_FEATS + (size_t)16*1024*64*4;
static constexpr size_t WS_NEED   = OFF_AGG + (size_t)16*1024*128*4;

// ---------------- tables ----------------
__global__ void init_tables(float* __restrict__ de, int* __restrict__ mp) {
  const int outs[5] = {64, 128, 256, 512, 1024};
  const int fds[5]  = {11, 22, 43, 86, 171};
  const int deo[5]  = {0, 11, 33, 76, 162};
  const int mpo[5]  = {0, 64, 192, 448, 960};
  const int tid = threadIdx.x;
  for (int c = 0; c < 5; ++c) {
    const int fd = fds[c], out = outs[c];
    for (int j = tid; j < fd; j += blockDim.x)
      de[deo[c] + j] = (float)pow(1000.0, (double)j / (double)fd);
    const double step = (double)(6 * fd - 1) / (double)(out - 1);
    for (int f = tid; f < out; f += blockDim.x)
      mp[mpo[c] + f] = (int)(step * (double)f);
  }
}

// ---------------- initial SPE embedding: feat0 [B,2048,64] ----------------
__global__ __launch_bounds__(256) void embed_init(const float* __restrict__ xyz,
                                                  float* __restrict__ feat,
                                                  const float* __restrict__ de,
                                                  const int* __restrict__ mp) {
  int g = blockIdx.x * blockDim.x + threadIdx.x;  // B*2048*64
  if (g >= BATCH * NPTS0 * 64) return;
  int c = g & 63;
  int bn = g >> 6;
  int m = mp[c];                 // cfg 0
  int sc = m & 1;                // 0=sin, 1=cos
  int a = m >> 1;
  int ci = a / 11;
  int j = a - ci * 11;
  float x = xyz[bn * 3 + ci];
  float ang = (100.0f * x) / de[j];
  feat[g] = sc ? cosf(ang) : sinf(ang);
}

// ---------------- FPS: ONE WAVE per batch, zero barriers ----------------
template <int PTS>
__device__ void fps_stage_wave(const float* lds_cur, float* lds_next, int S,
                               int* __restrict__ fps_idx, float* __restrict__ xyz_next) {
  const int lane = threadIdx.x;  // 0..63
  float px[PTS], py[PTS], pz[PTS], dist[PTS];
#pragma unroll
  for (int p = 0; p < PTS; ++p) {
    int gi = lane + p * 64;
    px[p] = lds_cur[3 * gi];
    py[p] = lds_cur[3 * gi + 1];
    pz[p] = lds_cur[3 * gi + 2];
    dist[p] = 1e10f;
  }
  unsigned sel = 0;
  if (lane == 0) {
    fps_idx[0] = 0;
    float a = lds_cur[0], b = lds_cur[1], c = lds_cur[2];
    xyz_next[0] = a; xyz_next[1] = b; xyz_next[2] = c;
    lds_next[0] = a; lds_next[1] = b; lds_next[2] = c;
  }
  for (int t = 1; t < S; ++t) {
    // broadcast read of current centroid (same address for all lanes)
    float cx = lds_cur[3 * sel], cy = lds_cur[3 * sel + 1], cz = lds_cur[3 * sel + 2];
    float bd = -1.0f;
    unsigned bi = 0u;
#pragma unroll
    for (int p = 0; p < PTS; ++p) {
      float dx = px[p] - cx, dy = py[p] - cy, dz = pz[p] - cz;
      float dd = dx * dx + dy * dy;
      dd = dd + dz * dz;                    // matches ((dx2+dy2)+dz2), contract off
      float nd = fminf(dist[p], dd);
      dist[p] = nd;
      unsigned gi = (unsigned)(lane + p * 64);
      if (nd > bd || (nd == bd && gi < bi)) { bd = nd; bi = gi; }
    }
    // butterfly argmax across the single wave (max d, tie -> min idx)
#pragma unroll
    for (int m = 1; m < 64; m <<= 1) {
      float od = __shfl_xor(bd, m);
      unsigned oi = __shfl_xor(bi, m);
      if (od > bd || (od == bd && oi < bi)) { bd = od; bi = oi; }
    }
    sel = bi;  // identical on all lanes after butterfly
    if (lane == 0) {
      fps_idx[t] = (int)sel;
      float a = lds_cur[3 * sel], b = lds_cur[3 * sel + 1], c = lds_cur[3 * sel + 2];
      xyz_next[3 * t] = a; xyz_next[3 * t + 1] = b; xyz_next[3 * t + 2] = c;
      lds_next[3 * t] = a; lds_next[3 * t + 1] = b; lds_next[3 * t + 2] = c;
    }
    // single wave: in-order LDS per wave, no barrier needed
  }
}

__global__ __launch_bounds__(64) void fps_all(const float* __restrict__ xyz0,
                                              float* __restrict__ xyz1, float* __restrict__ xyz2,
                                              float* __restrict__ xyz3, float* __restrict__ xyz4,
                                              int* __restrict__ i0, int* __restrict__ i1,
                                              int* __restrict__ i2, int* __restrict__ i3) {
  __shared__ float lds[3 * (2048 + 1024 + 512 + 256 + 128)];
  const int b = blockIdx.x;
  float* l0 = lds;
  float* l1 = l0 + 3 * 2048;
  float* l2 = l1 + 3 * 1024;
  float* l3 = l2 + 3 * 512;
  float* l4 = l3 + 3 * 256;
  for (int t = threadIdx.x; t < 3 * 2048; t += 64) l0[t] = xyz0[(size_t)b * 3 * 2048 + t];
  // one wave: loads above complete in-order before reads below (lgkmcnt)
  fps_stage_wave<32>(l0, l1, 1024, i0 + b * 1024, xyz1 + (size_t)b * 1024 * 3);
  fps_stage_wave<16>(l1, l2, 512, i1 + b * 512, xyz2 + (size_t)b * 512 * 3);
  fps_stage_wave<8>(l2, l3, 256, i2 + b * 256, xyz3 + (size_t)b * 256 * 3);
  fps_stage_wave<4>(l3, l4, 128, i3 + b * 128, xyz4 + (size_t)b * 128 * 3);
}

// ---------------- kNN: per-thread top-24 insertion over LDS database ----------------
__global__ __launch_bounds__(128) void knn_kernel(const float* __restrict__ db_xyz,
                                                  const float* __restrict__ q_xyz,
                                                  int* __restrict__ out_idx,
                                                  int Np, int S) {
  extern __shared__ float sm[];
  float* sx = sm;
  float* sy = sx + Np;
  float* sz = sy + Np;
  float* spn = sz + Np;
  float* kd = spn + Np;               // [KNN][128]
  int* ki = (int*)(kd + KNN * 128);   // [KNN][128]
  const int tid = threadIdx.x;
  const int bpb = (S + 127) / 128;
  const int b = blockIdx.x / bpb;
  const int qbase = (blockIdx.x % bpb) * 128;
  for (int j = tid; j < Np; j += 128) {
    float x = db_xyz[((size_t)b * Np + j) * 3 + 0];
    float y = db_xyz[((size_t)b * Np + j) * 3 + 1];
    float z = db_xyz[((size_t)b * Np + j) * 3 + 2];
    sx[j] = x; sy[j] = y; sz[j] = z;
    float pn = x * x + y * y;
    spn[j] = pn + z * z;
  }
  for (int e = 0; e < KNN; ++e) { kd[e * 128 + tid] = 3.4e38f; ki[e * 128 + tid] = 0; }
  __syncthreads();
  int s = qbase + tid;
  if (s >= S) return;
  float qx = q_xyz[((size_t)b * S + s) * 3 + 0];
  float qy = q_xyz[((size_t)b * S + s) * 3 + 1];
  float qz = q_xyz[((size_t)b * S + s) * 3 + 2];
  float qn = qx * qx + qy * qy;
  qn = qn + qz * qz;
  for (int j = 0; j < Np; ++j) {
    float dot = fmaf(qz, sz[j], fmaf(qy, sy[j], qx * sx[j]));
    float d = (qn + spn[j]) - 2.0f * dot;
    if (d < kd[23 * 128 + tid]) {     // strict <: ties keep lower (earlier) index
      int e = 23;
      while (e > 0 && kd[(e - 1) * 128 + tid] > d) {
        kd[e * 128 + tid] = kd[(e - 1) * 128 + tid];
        ki[e * 128 + tid] = ki[(e - 1) * 128 + tid];
        --e;
      }
      kd[e * 128 + tid] = d;
      ki[e * 128 + tid] = j;
    }
  }
  for (int e = 0; e < KNN; ++e) out_idx[((size_t)b * S + s) * KNN + e] = ki[e * 128 + tid];
}

// ---------------- gather feat_s ----------------
__global__ __launch_bounds__(256) void gather_feat_s(const float* __restrict__ feat,
                                                     const int* __restrict__ fidx,
                                                     float* __restrict__ out, int Np, int S, int C) {
  int g = blockIdx.x * blockDim.x + threadIdx.x;
  if (g >= BATCH * S * C) return;
  int c = g % C;
  int bs = g / C;
  int s = bs % S;
  int b = bs / S;
  int src = fidx[b * S + s];
  out[g] = feat[((size_t)b * Np + src) * C + c];
}

// ---------------- global std sums (xyz_c and feat_c), f64 ----------------
__global__ __launch_bounds__(256) void center_reduce(const float* __restrict__ xyz,
                                                     const float* __restrict__ xyz_s,
                                                     const float* __restrict__ feat,
                                                     const float* __restrict__ feat_s,
                                                     const int* __restrict__ kidx,
                                                     double* __restrict__ sums,
                                                     int Np, int S, int C) {
  int g = blockIdx.x * blockDim.x + threadIdx.x;
  int total = BATCH * S * KNN;
  double sx = 0, sxx = 0, sf = 0, sff = 0;
  if (g < total) {
    int bs = g / KNN;
    int s = bs % S;
    int b = bs / S;
    int j = kidx[g];
    const float* pc = xyz + ((size_t)b * Np + j) * 3;
    const float* qc = xyz_s + ((size_t)b * S + s) * 3;
    for (int c = 0; c < 3; ++c) {
      float v = pc[c] - qc[c];
      sx += (double)v;
      sxx += (double)v * (double)v;
    }
    const float4* fr = (const float4*)(feat + ((size_t)b * Np + j) * C);
    const float4* fs = (const float4*)(feat_s + ((size_t)b * S + s) * C);
    for (int c = 0; c < C / 4; ++c) {
      float4 a = fr[c], bq = fs[c];
      float v0 = a.x - bq.x, v1 = a.y - bq.y, v2 = a.z - bq.z, v3 = a.w - bq.w;
      sf += (double)v0 + (double)v1 + (double)v2 + (double)v3;
      sff += (double)v0 * v0 + (double)v1 * v1 + (double)v2 * v2 + (double)v3 * v3;
    }
  }
#pragma unroll
  for (int m = 1; m < 64; m <<= 1) {
    sx += __shfl_xor(sx, m);
    sxx += __shfl_xor(sxx, m);
    sf += __shfl_xor(sf, m);
    sff += __shfl_xor(sff, m);
  }
  __shared__ double part[4][4];
  int wv = threadIdx.x >> 6;
  if ((threadIdx.x & 63) == 0) { part[wv][0] = sx; part[wv][1] = sxx; part[wv][2] = sf; part[wv][3] = sff; }
  __syncthreads();
  if (threadIdx.x == 0) {
    double a = 0, b2 = 0, c2 = 0, d2 = 0;
    for (int w = 0; w < 4; ++w) { a += part[w][0]; b2 += part[w][1]; c2 += part[w][2]; d2 += part[w][3]; }
    atomicAdd(&sums[0], a);
    atomicAdd(&sums[1], b2);
    atomicAdd(&sums[2], c2);
    atomicAdd(&sums[3], d2);
  }
}

// ---------------- aggregation: wave per query, per-lane direct trig, NO LDS/barriers ----------------
template <int CH>  // channels per lane; D = CH*64 = 2C
__global__ __launch_bounds__(256) void agg_kernel(const float* __restrict__ xyz,
                                                  const float* __restrict__ xyz_s,
                                                  const float* __restrict__ feat,
                                                  const float* __restrict__ feat_s,
                                                  const int* __restrict__ kidx,
                                                  const double* __restrict__ csums,
                                                  const float* __restrict__ de,
                                                  const int* __restrict__ mp,
                                                  float* __restrict__ agg,
                                                  int Np, int S, int C, int fd,
                                                  double nx_d, double nf_d) {
  const int lane = threadIdx.x & 63;
  const int wv = threadIdx.x >> 6;
  const int q = blockIdx.x * 4 + wv;
  const int s = q % S;
  const int b = q / S;
  double sxd = csums[0], sxxd = csums[1], sfd = csums[2], sffd = csums[3];
  float stdx = sqrtf((float)((sxxd - sxd * sxd / nx_d) / (nx_d - 1.0)));
  float stdf = sqrtf((float)((sffd - sfd * sfd / nf_d) / (nf_d - 1.0)));
  float invx = 1.0f / (stdx + 1e-5f);
  float invf = 1.0f / (stdf + 1e-5f);
  float cx = xyz_s[((size_t)b * S + s) * 3 + 0];
  float cy = xyz_s[((size_t)b * S + s) * 3 + 1];
  float cz = xyz_s[((size_t)b * S + s) * 3 + 2];
  const float* fsrow = feat_s + ((size_t)b * S + s) * C;
  // per-channel decode: out_idx -> (sin/cos, coordinate, dim_embed value)
  int ci[CH];
  float dev[CH], fsv[CH];
  bool issin[CH], fh[CH];
#pragma unroll
  for (int ch = 0; ch < CH; ++ch) {
    int f = ch * 64 + lane;
    int m = mp[f];
    issin[ch] = (m & 1) == 0;
    int a = m >> 1;
    int cc = a / fd;
    ci[ch] = cc;
    dev[ch] = de[a - cc * fd];
    fh[ch] = f < C;
    fsv[ch] = fh[ch] ? fsrow[f] : fsrow[f - C];
  }
  float wmax[CH], wsum[CH];
#pragma unroll
  for (int ch = 0; ch < CH; ++ch) { wmax[ch] = -3.4e38f; wsum[ch] = 0.f; }
  const int* krow = kidx + ((size_t)b * S + s) * KNN;
  for (int k = 0; k < KNN; ++k) {
    int j = krow[k];  // wave-uniform
    const float* pr = xyz + ((size_t)b * Np + j) * 3;
    float n0 = (pr[0] - cx) * invx;
    float n1 = (pr[1] - cy) * invx;
    float n2 = (pr[2] - cz) * invx;
    const float* fr = feat + ((size_t)b * Np + j) * C;
#pragma unroll
    for (int ch = 0; ch < CH; ++ch) {
      float xv = (ci[ch] == 0) ? n0 : ((ci[ch] == 1) ? n1 : n2);
      float ang = (100.0f * xv) / dev[ch];
      float sv, cv;
      sincosf(ang, &sv, &cv);
      float pef = issin[ch] ? sv : cv;
      int f = ch * 64 + lane;
      float val = fh[ch] ? (fr[f] - fsv[ch]) * invf : fsv[ch];
      float w = (val + pef) * pef;
      wmax[ch] = fmaxf(wmax[ch], w);
      wsum[ch] += w;
    }
  }
  float* arow = agg + (size_t)q * (CH * 64);
#pragma unroll
  for (int ch = 0; ch < CH; ++ch) {
    int f = ch * 64 + lane;
    arow[f] = wmax[ch] + wsum[ch] / (float)KNN;
  }
}

// ---------------- BatchNorm reduce ----------------
__global__ __launch_bounds__(256) void bn_reduce(const float* __restrict__ agg,
                                                 double* __restrict__ bns,
                                                 int R, int D) {
  int r0 = blockIdx.x * 64;
  for (int c = threadIdx.x; c < D; c += 256) {
    double s = 0, ss = 0;
    for (int r = 0; r < 64; ++r) {
      float v = agg[(size_t)(r0 + r) * D + c];
      s += (double)v;
      ss += (double)v * (double)v;
    }
    atomicAdd(&bns[c], s);
    atomicAdd(&bns[D + c], ss);
  }
}

// ---------------- BatchNorm apply + exact GELU ----------------
__global__ __launch_bounds__(256) void bn_apply(const float* __restrict__ agg,
                                                const double* __restrict__ bns,
                                                const float* __restrict__ gamma,
                                                const float* __restrict__ beta,
                                                float* __restrict__ outf, int R, int D) {
  int g = blockIdx.x * blockDim.x + threadIdx.x;
  if (g >= R * D) return;
  int c = g % D;
  double n = (double)R;
  double mu = bns[c] / n;
  double var = bns[D + c] / n - mu * mu;  // biased
  float mean = (float)mu;
  float rstd = 1.0f / sqrtf((float)var + 1e-5f);
  float x = (agg[g] - mean) * rstd;
  float y = gamma[c] * x + beta[c];
  float e = erff(y * 0.70710678118654752440f);
  outf[g] = 0.5f * y * (1.0f + e);
}

// ---------------- final: max + mean over S=128 ----------------
__global__ __launch_bounds__(256) void final_kernel(const float* __restrict__ feat,
                                                    float* __restrict__ out) {
  int g = blockIdx.x * blockDim.x + threadIdx.x;  // B*1024
  if (g >= BATCH * 1024) return;
  int f = g % 1024;
  int b = g / 1024;
  const float* base = feat + (size_t)b * 128 * 1024 + f;
  float mx = -3.4e38f;
  float sm = 0.f;
  for (int s = 0; s < 128; ++s) {
    float v = base[(size_t)s * 1024];
    mx = fmaxf(mx, v);
    sm += v;
  }
  out[g] = mx + sm / 128.0f;
}

// ---------------- host ----------------
extern "C" void kernel_launch(void* const* d_in, const int* in_sizes, int n_in,
                              void* d_out, int out_size, void* d_ws, size_t ws_size,
                              hipStream_t stream) {
  (void)in_sizes; (void)n_in; (void)out_size;
  if (ws_size < WS_NEED) return;
  const float* xyz = (const float*)d_in[0];
  const float* gam[4] = {(const float*)d_in[1], (const float*)d_in[3], (const float*)d_in[5], (const float*)d_in[7]};
  const float* bet[4] = {(const float*)d_in[2], (const float*)d_in[4], (const float*)d_in[6], (const float*)d_in[8]};
  char* ws = (char*)d_ws;
  double* stats = (double*)(ws + OFF_STATS);
  double* bns = (double*)(ws + OFF_BN);
  float* de = (float*)(ws + OFF_DE);
  int* mp = (int*)(ws + OFF_MAP);
  float* xyz1 = (float*)(ws + OFF_XYZ1);
  float* xyz2 = (float*)(ws + OFF_XYZ2);
  float* xyz3 = (float*)(ws + OFF_XYZ3);
  float* xyz4 = (float*)(ws + OFF_XYZ4);
  int* fpsI[4] = {(int*)(ws + OFF_FPS0), (int*)(ws + OFF_FPS1), (int*)(ws + OFF_FPS2), (int*)(ws + OFF_FPS3)};
  int* kidx = (int*)(ws + OFF_KNN);
  float* feata = (float*)(ws + OFF_FEATA);
  float* featb = (float*)(ws + OFF_FEATB);
  float* feats = (float*)(ws + OFF_FEATS);
  float* agg = (float*)(ws + OFF_AGG);

  hipMemsetAsync(ws, 0, 32768, stream);
  init_tables<<<1, 256, 0, stream>>>(de, mp);
  fps_all<<<16, 64, 0, stream>>>(xyz, xyz1, xyz2, xyz3, xyz4, fpsI[0], fpsI[1], fpsI[2], fpsI[3]);
  embed_init<<<(BATCH * NPTS0 * 64) / 256, 256, 0, stream>>>(xyz, feata, de, mp);

  const int Ns[4] = {2048, 1024, 512, 256};
  const int Cs[4] = {64, 128, 256, 512};
  const int fdv[4] = {22, 43, 86, 171};
  const int deo[4] = {11, 33, 76, 162};
  const int mpo[4] = {64, 192, 448, 960};
  const float* xin[5] = {xyz, xyz1, xyz2, xyz3, xyz4};
  float* fcur = feata;
  float* fnext = featb;
  int bnoff = 0;
  for (int i = 0; i < 4; ++i) {
    const int Np = Ns[i], S = Np / 2, C = Cs[i], D = 2 * C;
    const int bpb = S / 128;
    size_t knn_lds = (size_t)(4 * Np + 2 * KNN * 128) * 4;
    knn_kernel<<<16 * bpb, 128, knn_lds, stream>>>(xin[i], xin[i + 1], kidx, Np, S);
    gather_feat_s<<<(BATCH * S * C) / 256, 256, 0, stream>>>(fcur, fpsI[i], feats, Np, S, C);
    const int tuples = BATCH * S * KNN;
    center_reduce<<<(tuples + 255) / 256, 256, 0, stream>>>(xin[i], xin[i + 1], fcur, feats, kidx,
                                                            stats + 4 * i, Np, S, C);
    double nx = (double)tuples * 3.0;
    double nf = (double)tuples * (double)C;
    dim3 ag((BATCH * S) / 4);
    switch (D / 64) {
      case 2:
        agg_kernel<2><<<ag, 256, 0, stream>>>(xin[i], xin[i + 1], fcur, feats, kidx, stats + 4 * i,
                                              de + deo[i], mp + mpo[i], agg, Np, S, C, fdv[i], nx, nf);
        break;
      case 4:
        agg_kernel<4><<<ag, 256, 0, stream>>>(xin[i], xin[i + 1], fcur, feats, kidx, stats + 4 * i,
                                              de + deo[i], mp + mpo[i], agg, Np, S, C, fdv[i], nx, nf);
        break;
      case 8:
        agg_kernel<8><<<ag, 256, 0, stream>>>(xin[i], xin[i + 1], fcur, feats, kidx, stats + 4 * i,
                                              de + deo[i], mp + mpo[i], agg, Np, S, C, fdv[i], nx, nf);
        break;
      default:
        agg_kernel<16><<<ag, 256, 0, stream>>>(xin[i], xin[i + 1], fcur, feats, kidx, stats + 4 * i,
                                               de + deo[i], mp + mpo[i], agg, Np, S, C, fdv[i], nx, nf);
        break;
    }
    const int R = BATCH * S;
    bn_reduce<<<R / 64, 256, 0, stream>>>(agg, bns + bnoff, R, D);
    bn_apply<<<(R * D) / 256, 256, 0, stream>>>(agg, bns + bnoff, gam[i], bet[i], fnext, R, D);
    bnoff += 2 * D;
    float* t = fcur; fcur = fnext; fnext = t;
  }
  final_kernel<<<(BATCH * 1024) / 256, 256, 0, stream>>>(fcur, (float*)d_out);
}

// Round 3
// 3284.650 us; speedup vs baseline: 2.1520x; 2.1520x over previous
//
#include <hip/hip_runtime.h>
#include <math.h>

#pragma clang fp contract(off)

static constexpr int BATCH = 16;
static constexpr int NPTS0 = 2048;
static constexpr int KNN = 24;

// ---------------- workspace layout (bytes) ----------------
static constexpr size_t OFF_STATS = 0;                         // 4 stages * 4 doubles
static constexpr size_t OFF_BN    = 256;                       // (128+256+512+1024)*2 doubles
static constexpr size_t OFF_DE    = 32768;                     // 333 floats (dim_embed tables)
static constexpr size_t OFF_MAP   = 36864;                     // 1984 ints (out_idx tables)
static constexpr size_t OFF_XYZ1  = 49152;                                      // 16*1024*3 f32
static constexpr size_t OFF_XYZ2  = OFF_XYZ1 + (size_t)16*1024*3*4;
static constexpr size_t OFF_XYZ3  = OFF_XYZ2 + (size_t)16*512*3*4;
static constexpr size_t OFF_XYZ4  = OFF_XYZ3 + (size_t)16*256*3*4;
static constexpr size_t OFF_FPS0  = OFF_XYZ4 + (size_t)16*128*3*4;
static constexpr size_t OFF_FPS1  = OFF_FPS0 + (size_t)16*1024*4;
static constexpr size_t OFF_FPS2  = OFF_FPS1 + (size_t)16*512*4;
static constexpr size_t OFF_FPS3  = OFF_FPS2 + (size_t)16*256*4;
static constexpr size_t OFF_KNN   = OFF_FPS3 + (size_t)16*128*4;                // 16*1024*24 ints
static constexpr size_t OFF_FEATA = OFF_KNN + (size_t)16*1024*24*4;
static constexpr size_t OFF_FEATB = OFF_FEATA + (size_t)16*2048*64*4;
static constexpr size_t OFF_FEATS = OFF_FEATB + (size_t)16*2048*64*4;
static constexpr size_t OFF_AGG   = OFF_FEATS + (size_t)16*1024*64*4;
static constexpr size_t WS_NEED   = OFF_AGG + (size_t)16*1024*128*4;

// ---------------- u64 key helpers ----------------
__device__ inline uint64_t kmax64(uint64_t a, uint64_t b) { return a > b ? a : b; }
__device__ inline uint64_t kmin64(uint64_t a, uint64_t b) { return a < b ? a : b; }

template <int CTRL>
__device__ inline uint64_t dpp_shift64(uint64_t k) {
  int hi = (int)(unsigned)(k >> 32), lo = (int)(unsigned)k;
  int oh = __builtin_amdgcn_update_dpp(hi, hi, CTRL, 0xF, 0xF, false);
  int ol = __builtin_amdgcn_update_dpp(lo, lo, CTRL, 0xF, 0xF, false);
  return ((uint64_t)(unsigned)oh << 32) | (unsigned)ol;
}
// max-reduce across the wave; result valid in lane 63. DPP = VALU latency, no DS pipe.
__device__ inline uint64_t wave_reduce_max64(uint64_t k) {
  k = kmax64(k, dpp_shift64<0x111>(k));  // row_shr:1
  k = kmax64(k, dpp_shift64<0x112>(k));  // row_shr:2
  k = kmax64(k, dpp_shift64<0x114>(k));  // row_shr:4
  k = kmax64(k, dpp_shift64<0x118>(k));  // row_shr:8
  k = kmax64(k, dpp_shift64<0x142>(k));  // row_bcast:15
  k = kmax64(k, dpp_shift64<0x143>(k));  // row_bcast:31
  return k;
}

__device__ inline unsigned sortable_f32(float f) {
  unsigned b = __float_as_uint(f);
  unsigned m = (unsigned)((int)b >> 31) | 0x80000000u;
  return b ^ m;  // total order: u32 compare == float compare
}

// ---------------- tables ----------------
__global__ void init_tables(float* __restrict__ de, int* __restrict__ mp) {
  const int outs[5] = {64, 128, 256, 512, 1024};
  const int fds[5]  = {11, 22, 43, 86, 171};
  const int deo[5]  = {0, 11, 33, 76, 162};
  const int mpo[5]  = {0, 64, 192, 448, 960};
  const int tid = threadIdx.x;
  for (int c = 0; c < 5; ++c) {
    const int fd = fds[c], out = outs[c];
    for (int j = tid; j < fd; j += blockDim.x)
      de[deo[c] + j] = (float)pow(1000.0, (double)j / (double)fd);
    const double step = (double)(6 * fd - 1) / (double)(out - 1);
    for (int f = tid; f < out; f += blockDim.x)
      mp[mpo[c] + f] = (int)(step * (double)f);
  }
}

// ---------------- initial SPE embedding ----------------
__global__ __launch_bounds__(256) void embed_init(const float* __restrict__ xyz,
                                                  float* __restrict__ feat,
                                                  const float* __restrict__ de,
                                                  const int* __restrict__ mp) {
  int g = blockIdx.x * blockDim.x + threadIdx.x;
  if (g >= BATCH * NPTS0 * 64) return;
  int c = g & 63;
  int bn = g >> 6;
  int m = mp[c];
  int sc = m & 1;
  int a = m >> 1;
  int ci = a / 11;
  int j = a - ci * 11;
  float x = xyz[bn * 3 + ci];
  float ang = (100.0f * x) / de[j];
  feat[g] = sc ? cosf(ang) : sinf(ang);
}

// ---------------- FPS: 256 threads, DPP reduce, 1 barrier/iter ----------------
template <int PTS>  // N = PTS*256 input points, S = N/2 selected
__device__ void fps_stage(const float* lds_cur, float* lds_next,
                          int* __restrict__ fps_idx, float* __restrict__ xyz_next,
                          uint64_t* red /*[2][4]*/) {
  const int N = PTS * 256, S = PTS * 128;
  const int tid = threadIdx.x;
  __syncthreads();  // prev stage's lds_next writes -> visible
  float px[PTS], py[PTS], pz[PTS], dist[PTS];
  const unsigned nl = ~(unsigned)tid;
#pragma unroll
  for (int p = 0; p < PTS; ++p) {
    int gi = tid + p * 256;
    px[p] = lds_cur[3 * gi];
    py[p] = lds_cur[3 * gi + 1];
    pz[p] = lds_cur[3 * gi + 2];
    dist[p] = 1e10f;
  }
  unsigned sel = 0;
  if (tid == 0) {
    fps_idx[0] = 0;
    float a = lds_cur[0], b = lds_cur[1], c = lds_cur[2];
    xyz_next[0] = a; xyz_next[1] = b; xyz_next[2] = c;
    lds_next[0] = a; lds_next[1] = b; lds_next[2] = c;
  }
  for (int t = 1; t < S; ++t) {
    float cx = lds_cur[3 * sel], cy = lds_cur[3 * sel + 1], cz = lds_cur[3 * sel + 2];
    uint64_t kb = 0;
#pragma unroll
    for (int p = 0; p < PTS; ++p) {
      float dx = px[p] - cx, dy = py[p] - cy, dz = pz[p] - cz;
      float dd = dx * dx + dy * dy;
      dd = dd + dz * dz;                    // ((dx2+dy2)+dz2), contract off
      float nd = fminf(dist[p], dd);
      dist[p] = nd;
      // key: (f32 bits of d)<<32 | ~gi  -- d>=0 so u64 max == (max d, tie -> min gi)
      uint64_t key = ((uint64_t)__float_as_uint(nd) << 32) | (unsigned)(nl - (unsigned)(p * 256));
      kb = kmax64(kb, key);
    }
    kb = wave_reduce_max64(kb);
    if ((tid & 63) == 63) red[(t & 1) * 4 + (tid >> 6)] = kb;
    __syncthreads();
    uint64_t k0 = red[(t & 1) * 4 + 0], k1 = red[(t & 1) * 4 + 1];
    uint64_t k2 = red[(t & 1) * 4 + 2], k3 = red[(t & 1) * 4 + 3];
    uint64_t km = kmax64(kmax64(k0, k1), kmax64(k2, k3));
    sel = ~(unsigned)km;
    if (tid == 0) {
      fps_idx[t] = (int)sel;
      float a = lds_cur[3 * sel], b = lds_cur[3 * sel + 1], c = lds_cur[3 * sel + 2];
      xyz_next[3 * t] = a; xyz_next[3 * t + 1] = b; xyz_next[3 * t + 2] = c;
      lds_next[3 * t] = a; lds_next[3 * t + 1] = b; lds_next[3 * t + 2] = c;
    }
    // no 2nd barrier: red is parity-double-buffered; barrier(t+1) orders reuse
  }
}

__global__ __launch_bounds__(256) void fps_all(const float* __restrict__ xyz0,
                                               float* __restrict__ xyz1, float* __restrict__ xyz2,
                                               float* __restrict__ xyz3, float* __restrict__ xyz4,
                                               int* __restrict__ i0, int* __restrict__ i1,
                                               int* __restrict__ i2, int* __restrict__ i3) {
  __shared__ float lds[3 * (2048 + 1024 + 512 + 256 + 128)];
  __shared__ uint64_t red[8];
  const int b = blockIdx.x;
  float* l0 = lds;
  float* l1 = l0 + 3 * 2048;
  float* l2 = l1 + 3 * 1024;
  float* l3 = l2 + 3 * 512;
  float* l4 = l3 + 3 * 256;
  for (int t = threadIdx.x; t < 3 * 2048; t += 256) l0[t] = xyz0[(size_t)b * 3 * 2048 + t];
  fps_stage<8>(l0, l1, i0 + b * 1024, xyz1 + (size_t)b * 1024 * 3, red);
  fps_stage<4>(l1, l2, i1 + b * 512, xyz2 + (size_t)b * 512 * 3, red);
  fps_stage<2>(l2, l3, i2 + b * 256, xyz3 + (size_t)b * 256 * 3, red);
  fps_stage<1>(l3, l4, i3 + b * 128, xyz4 + (size_t)b * 128 * 3, red);
}

// ---------------- kNN: register-resident sorted top-24 (u64 keys) ----------------
// key = (sortable(d)<<32)|j : ascending u64 order == top_k order (d asc, tie j asc)
__global__ __launch_bounds__(64) void knn_kernel(const float* __restrict__ db_xyz,
                                                 const float* __restrict__ q_xyz,
                                                 int* __restrict__ out_idx,
                                                 int Np, int S) {
  extern __shared__ float4 sdb[];  // [Np] = {x, y, z, |p|^2}
  const int tid = threadIdx.x;
  const int bpb = S >> 6;
  const int b = blockIdx.x / bpb;
  const int s = (blockIdx.x % bpb) * 64 + tid;
  for (int j = tid; j < Np; j += 64) {
    float x = db_xyz[((size_t)b * Np + j) * 3 + 0];
    float y = db_xyz[((size_t)b * Np + j) * 3 + 1];
    float z = db_xyz[((size_t)b * Np + j) * 3 + 2];
    float pn = x * x + y * y;
    pn = pn + z * z;                 // matches jnp.sum(xyz**2,-1)
    sdb[j] = make_float4(x, y, z, pn);
  }
  __syncthreads();
  float qx = q_xyz[((size_t)b * S + s) * 3 + 0];
  float qy = q_xyz[((size_t)b * S + s) * 3 + 1];
  float qz = q_xyz[((size_t)b * S + s) * 3 + 2];
  float qn = qx * qx + qy * qy;
  qn = qn + qz * qz;
  uint64_t kk[KNN];
#pragma unroll
  for (int e = 0; e < KNN; ++e) kk[e] = ~0ull;
  for (int j = 0; j < Np; ++j) {
    float4 p = sdb[j];  // uniform address -> broadcast read
    // Eigen/XLA fma-chain dot, then (qn+pn) - 2*dot
    float dot = fmaf(qz, p.z, fmaf(qy, p.y, qx * p.x));
    float d = (qn + p.w) - 2.0f * dot;
    uint64_t ck = ((uint64_t)sortable_f32(d) << 32) | (unsigned)j;
    bool pass = ck < kk[KNN - 1];
    if (__any(pass)) {
      uint64_t v = pass ? ck : ~0ull;
#pragma unroll
      for (int e = 0; e < KNN; ++e) {  // sorted-insert ladder, register-only
        uint64_t mn = kmin64(kk[e], v);
        uint64_t mx = kmax64(kk[e], v);
        kk[e] = mn;
        v = mx;
      }
    }
  }
#pragma unroll
  for (int e = 0; e < KNN; ++e)
    out_idx[((size_t)b * S + s) * KNN + e] = (int)(unsigned)kk[e];
}

// ---------------- gather feat_s ----------------
__global__ __launch_bounds__(256) void gather_feat_s(const float* __restrict__ feat,
                                                     const int* __restrict__ fidx,
                                                     float* __restrict__ out, int Np, int S, int C) {
  int g = blockIdx.x * blockDim.x + threadIdx.x;
  if (g >= BATCH * S * C) return;
  int c = g % C;
  int bs = g / C;
  int s = bs % S;
  int b = bs / S;
  int src = fidx[b * S + s];
  out[g] = feat[((size_t)b * Np + src) * C + c];
}

// ---------------- global std sums (xyz_c and feat_c), f64 ----------------
__global__ __launch_bounds__(256) void center_reduce(const float* __restrict__ xyz,
                                                     const float* __restrict__ xyz_s,
                                                     const float* __restrict__ feat,
                                                     const float* __restrict__ feat_s,
                                                     const int* __restrict__ kidx,
                                                     double* __restrict__ sums,
                                                     int Np, int S, int C) {
  int g = blockIdx.x * blockDim.x + threadIdx.x;
  int total = BATCH * S * KNN;
  double sx = 0, sxx = 0, sf = 0, sff = 0;
  if (g < total) {
    int bs = g / KNN;
    int s = bs % S;
    int b = bs / S;
    int j = kidx[g];
    const float* pc = xyz + ((size_t)b * Np + j) * 3;
    const float* qc = xyz_s + ((size_t)b * S + s) * 3;
    for (int c = 0; c < 3; ++c) {
      float v = pc[c] - qc[c];
      sx += (double)v;
      sxx += (double)v * (double)v;
    }
    const float4* fr = (const float4*)(feat + ((size_t)b * Np + j) * C);
    const float4* fs = (const float4*)(feat_s + ((size_t)b * S + s) * C);
    for (int c = 0; c < C / 4; ++c) {
      float4 a = fr[c], bq = fs[c];
      float v0 = a.x - bq.x, v1 = a.y - bq.y, v2 = a.z - bq.z, v3 = a.w - bq.w;
      sf += (double)v0 + (double)v1 + (double)v2 + (double)v3;
      sff += (double)v0 * v0 + (double)v1 * v1 + (double)v2 * v2 + (double)v3 * v3;
    }
  }
#pragma unroll
  for (int m = 1; m < 64; m <<= 1) {
    sx += __shfl_xor(sx, m);
    sxx += __shfl_xor(sxx, m);
    sf += __shfl_xor(sf, m);
    sff += __shfl_xor(sff, m);
  }
  __shared__ double part[4][4];
  int wv = threadIdx.x >> 6;
  if ((threadIdx.x & 63) == 0) { part[wv][0] = sx; part[wv][1] = sxx; part[wv][2] = sf; part[wv][3] = sff; }
  __syncthreads();
  if (threadIdx.x == 0) {
    double a = 0, b2 = 0, c2 = 0, d2 = 0;
    for (int w = 0; w < 4; ++w) { a += part[w][0]; b2 += part[w][1]; c2 += part[w][2]; d2 += part[w][3]; }
    atomicAdd(&sums[0], a);
    atomicAdd(&sums[1], b2);
    atomicAdd(&sums[2], c2);
    atomicAdd(&sums[3], d2);
  }
}

// ---------------- aggregation: wave per query, per-lane direct trig ----------------
template <int CH>
__global__ __launch_bounds__(256) void agg_kernel(const float* __restrict__ xyz,
                                                  const float* __restrict__ xyz_s,
                                                  const float* __restrict__ feat,
                                                  const float* __restrict__ feat_s,
                                                  const int* __restrict__ kidx,
                                                  const double* __restrict__ csums,
                                                  const float* __restrict__ de,
                                                  const int* __restrict__ mp,
                                                  float* __restrict__ agg,
                                                  int Np, int S, int C, int fd,
                                                  double nx_d, double nf_d) {
  const int lane = threadIdx.x & 63;
  const int wv = threadIdx.x >> 6;
  const int q = blockIdx.x * 4 + wv;
  const int s = q % S;
  const int b = q / S;
  double sxd = csums[0], sxxd = csums[1], sfd = csums[2], sffd = csums[3];
  float stdx = sqrtf((float)((sxxd - sxd * sxd / nx_d) / (nx_d - 1.0)));
  float stdf = sqrtf((float)((sffd - sfd * sfd / nf_d) / (nf_d - 1.0)));
  float invx = 1.0f / (stdx + 1e-5f);
  float invf = 1.0f / (stdf + 1e-5f);
  float cx = xyz_s[((size_t)b * S + s) * 3 + 0];
  float cy = xyz_s[((size_t)b * S + s) * 3 + 1];
  float cz = xyz_s[((size_t)b * S + s) * 3 + 2];
  const float* fsrow = feat_s + ((size_t)b * S + s) * C;
  int ci[CH];
  float dev[CH], fsv[CH];
  bool issin[CH], fh[CH];
#pragma unroll
  for (int ch = 0; ch < CH; ++ch) {
    int f = ch * 64 + lane;
    int m = mp[f];
    issin[ch] = (m & 1) == 0;
    int a = m >> 1;
    int cc = a / fd;
    ci[ch] = cc;
    dev[ch] = de[a - cc * fd];
    fh[ch] = f < C;
    fsv[ch] = fh[ch] ? fsrow[f] : fsrow[f - C];
  }
  float wmax[CH], wsum[CH];
#pragma unroll
  for (int ch = 0; ch < CH; ++ch) { wmax[ch] = -3.4e38f; wsum[ch] = 0.f; }
  const int* krow = kidx + ((size_t)b * S + s) * KNN;
  for (int k = 0; k < KNN; ++k) {
    int j = krow[k];
    const float* pr = xyz + ((size_t)b * Np + j) * 3;
    float n0 = (pr[0] - cx) * invx;
    float n1 = (pr[1] - cy) * invx;
    float n2 = (pr[2] - cz) * invx;
    const float* fr = feat + ((size_t)b * Np + j) * C;
#pragma unroll
    for (int ch = 0; ch < CH; ++ch) {
      float xv = (ci[ch] == 0) ? n0 : ((ci[ch] == 1) ? n1 : n2);
      float ang = (100.0f * xv) / dev[ch];
      float sv, cv;
      sincosf(ang, &sv, &cv);
      float pef = issin[ch] ? sv : cv;
      int f = ch * 64 + lane;
      float val = fh[ch] ? (fr[f] - fsv[ch]) * invf : fsv[ch];
      float w = (val + pef) * pef;
      wmax[ch] = fmaxf(wmax[ch], w);
      wsum[ch] += w;
    }
  }
  float* arow = agg + (size_t)q * (CH * 64);
#pragma unroll
  for (int ch = 0; ch < CH; ++ch) {
    int f = ch * 64 + lane;
    arow[f] = wmax[ch] + wsum[ch] / (float)KNN;
  }
}

// ---------------- BatchNorm reduce ----------------
__global__ __launch_bounds__(256) void bn_reduce(const float* __restrict__ agg,
                                                 double* __restrict__ bns,
                                                 int R, int D) {
  int r0 = blockIdx.x * 64;
  for (int c = threadIdx.x; c < D; c += 256) {
    double s = 0, ss = 0;
    for (int r = 0; r < 64; ++r) {
      float v = agg[(size_t)(r0 + r) * D + c];
      s += (double)v;
      ss += (double)v * (double)v;
    }
    atomicAdd(&bns[c], s);
    atomicAdd(&bns[D + c], ss);
  }
}

// ---------------- BatchNorm apply + exact GELU ----------------
__global__ __launch_bounds__(256) void bn_apply(const float* __restrict__ agg,
                                                const double* __restrict__ bns,
                                                const float* __restrict__ gamma,
                                                const float* __restrict__ beta,
                                                float* __restrict__ outf, int R, int D) {
  int g = blockIdx.x * blockDim.x + threadIdx.x;
  if (g >= R * D) return;
  int c = g % D;
  double n = (double)R;
  double mu = bns[c] / n;
  double var = bns[D + c] / n - mu * mu;  // biased
  float mean = (float)mu;
  float rstd = 1.0f / sqrtf((float)var + 1e-5f);
  float x = (agg[g] - mean) * rstd;
  float y = gamma[c] * x + beta[c];
  float e = erff(y * 0.70710678118654752440f);
  outf[g] = 0.5f * y * (1.0f + e);
}

// ---------------- final: max + mean over S=128 ----------------
__global__ __launch_bounds__(256) void final_kernel(const float* __restrict__ feat,
                                                    float* __restrict__ out) {
  int g = blockIdx.x * blockDim.x + threadIdx.x;
  if (g >= BATCH * 1024) return;
  int f = g % 1024;
  int b = g / 1024;
  const float* base = feat + (size_t)b * 128 * 1024 + f;
  float mx = -3.4e38f;
  float sm = 0.f;
  for (int s = 0; s < 128; ++s) {
    float v = base[(size_t)s * 1024];
    mx = fmaxf(mx, v);
    sm += v;
  }
  out[g] = mx + sm / 128.0f;
}

// ---------------- host ----------------
extern "C" void kernel_launch(void* const* d_in, const int* in_sizes, int n_in,
                              void* d_out, int out_size, void* d_ws, size_t ws_size,
                              hipStream_t stream) {
  (void)in_sizes; (void)n_in; (void)out_size;
  if (ws_size < WS_NEED) return;
  const float* xyz = (const float*)d_in[0];
  const float* gam[4] = {(const float*)d_in[1], (const float*)d_in[3], (const float*)d_in[5], (const float*)d_in[7]};
  const float* bet[4] = {(const float*)d_in[2], (const float*)d_in[4], (const float*)d_in[6], (const float*)d_in[8]};
  char* ws = (char*)d_ws;
  double* stats = (double*)(ws + OFF_STATS);
  double* bns = (double*)(ws + OFF_BN);
  float* de = (float*)(ws + OFF_DE);
  int* mp = (int*)(ws + OFF_MAP);
  float* xyz1 = (float*)(ws + OFF_XYZ1);
  float* xyz2 = (float*)(ws + OFF_XYZ2);
  float* xyz3 = (float*)(ws + OFF_XYZ3);
  float* xyz4 = (float*)(ws + OFF_XYZ4);
  int* fpsI[4] = {(int*)(ws + OFF_FPS0), (int*)(ws + OFF_FPS1), (int*)(ws + OFF_FPS2), (int*)(ws + OFF_FPS3)};
  int* kidx = (int*)(ws + OFF_KNN);
  float* feata = (float*)(ws + OFF_FEATA);
  float* featb = (float*)(ws + OFF_FEATB);
  float* feats = (float*)(ws + OFF_FEATS);
  float* agg = (float*)(ws + OFF_AGG);

  hipMemsetAsync(ws, 0, 32768, stream);
  init_tables<<<1, 256, 0, stream>>>(de, mp);
  fps_all<<<16, 256, 0, stream>>>(xyz, xyz1, xyz2, xyz3, xyz4, fpsI[0], fpsI[1], fpsI[2], fpsI[3]);
  embed_init<<<(BATCH * NPTS0 * 64) / 256, 256, 0, stream>>>(xyz, feata, de, mp);

  const int Ns[4] = {2048, 1024, 512, 256};
  const int Cs[4] = {64, 128, 256, 512};
  const int fdv[4] = {22, 43, 86, 171};
  const int deo[4] = {11, 33, 76, 162};
  const int mpo[4] = {64, 192, 448, 960};
  const float* xin[5] = {xyz, xyz1, xyz2, xyz3, xyz4};
  float* fcur = feata;
  float* fnext = featb;
  int bnoff = 0;
  for (int i = 0; i < 4; ++i) {
    const int Np = Ns[i], S = Np / 2, C = Cs[i], D = 2 * C;
    size_t knn_lds = (size_t)Np * 16;
    knn_kernel<<<16 * (S / 64), 64, knn_lds, stream>>>(xin[i], xin[i + 1], kidx, Np, S);
    gather_feat_s<<<(BATCH * S * C) / 256, 256, 0, stream>>>(fcur, fpsI[i], feats, Np, S, C);
    const int tuples = BATCH * S * KNN;
    center_reduce<<<(tuples + 255) / 256, 256, 0, stream>>>(xin[i], xin[i + 1], fcur, feats, kidx,
                                                            stats + 4 * i, Np, S, C);
    double nx = (double)tuples * 3.0;
    double nf = (double)tuples * (double)C;
    dim3 ag((BATCH * S) / 4);
    switch (D / 64) {
      case 2:
        agg_kernel<2><<<ag, 256, 0, stream>>>(xin[i], xin[i + 1], fcur, feats, kidx, stats + 4 * i,
                                              de + deo[i], mp + mpo[i], agg, Np, S, C, fdv[i], nx, nf);
        break;
      case 4:
        agg_kernel<4><<<ag, 256, 0, stream>>>(xin[i], xin[i + 1], fcur, feats, kidx, stats + 4 * i,
                                              de + deo[i], mp + mpo[i], agg, Np, S, C, fdv[i], nx, nf);
        break;
      case 8:
        agg_kernel<8><<<ag, 256, 0, stream>>>(xin[i], xin[i + 1], fcur, feats, kidx, stats + 4 * i,
                                              de + deo[i], mp + mpo[i], agg, Np, S, C, fdv[i], nx, nf);
        break;
      default:
        agg_kernel<16><<<ag, 256, 0, stream>>>(xin[i], xin[i + 1], fcur, feats, kidx, stats + 4 * i,
                                               de + deo[i], mp + mpo[i], agg, Np, S, C, fdv[i], nx, nf);
        break;
    }
    const int R = BATCH * S;
    bn_reduce<<<R / 64, 256, 0, stream>>>(agg, bns + bnoff, R, D);
    bn_apply<<<(R * D) / 256, 256, 0, stream>>>(agg, bns + bnoff, gam[i], bet[i], fnext, R, D);
    bnoff += 2 * D;
    float* t = fcur; fcur = fnext; fnext = t;
  }
  final_kernel<<<(BATCH * 1024) / 256, 256, 0, stream>>>(fcur, (float*)d_out);
}

// Round 4
// 1753.359 us; speedup vs baseline: 4.0315x; 1.8733x over previous
//
#include <hip/hip_runtime.h>
#include <math.h>

#pragma clang fp contract(off)

static constexpr int BATCH = 16;
static constexpr int NPTS0 = 2048;
static constexpr int KNN = 24;

// ---------------- workspace layout (bytes) ----------------
static constexpr size_t OFF_STATS = 0;                         // 4 stages * 4 doubles
static constexpr size_t OFF_BN    = 256;                       // (128+256+512+1024)*2 doubles
static constexpr size_t OFF_DE    = 32768;                     // 333 floats (dim_embed tables)
static constexpr size_t OFF_MAP   = 36864;                     // 1984 ints (out_idx tables)
static constexpr size_t OFF_XYZ1  = 49152;                                      // 16*1024*3 f32
static constexpr size_t OFF_XYZ2  = OFF_XYZ1 + (size_t)16*1024*3*4;
static constexpr size_t OFF_XYZ3  = OFF_XYZ2 + (size_t)16*512*3*4;
static constexpr size_t OFF_XYZ4  = OFF_XYZ3 + (size_t)16*256*3*4;
static constexpr size_t OFF_FPS0  = OFF_XYZ4 + (size_t)16*128*3*4;
static constexpr size_t OFF_FPS1  = OFF_FPS0 + (size_t)16*1024*4;
static constexpr size_t OFF_FPS2  = OFF_FPS1 + (size_t)16*512*4;
static constexpr size_t OFF_FPS3  = OFF_FPS2 + (size_t)16*256*4;
static constexpr size_t OFF_KNN   = OFF_FPS3 + (size_t)16*128*4;                // 16*1024*24 ints
static constexpr size_t OFF_FEATA = OFF_KNN + (size_t)16*1024*24*4;
static constexpr size_t OFF_FEATB = OFF_FEATA + (size_t)16*2048*64*4;
static constexpr size_t OFF_FEATS = OFF_FEATB + (size_t)16*2048*64*4;           // also reused as tau (u32[16*1024]) before gather
static constexpr size_t OFF_AGG   = OFF_FEATS + (size_t)16*1024*64*4;
static constexpr size_t WS_NEED   = OFF_AGG + (size_t)16*1024*128*4;

// ---------------- helpers ----------------
__device__ inline uint64_t kmax64(uint64_t a, uint64_t b) { return a > b ? a : b; }

template <int CTRL>
__device__ inline uint64_t dpp_shift64(uint64_t k) {
  int hi = (int)(unsigned)(k >> 32), lo = (int)(unsigned)k;
  int oh = __builtin_amdgcn_update_dpp(hi, hi, CTRL, 0xF, 0xF, false);
  int ol = __builtin_amdgcn_update_dpp(lo, lo, CTRL, 0xF, 0xF, false);
  return ((uint64_t)(unsigned)oh << 32) | (unsigned)ol;
}
__device__ inline uint64_t wave_reduce_max64(uint64_t k) {
  k = kmax64(k, dpp_shift64<0x111>(k));  // row_shr:1
  k = kmax64(k, dpp_shift64<0x112>(k));  // row_shr:2
  k = kmax64(k, dpp_shift64<0x114>(k));  // row_shr:4
  k = kmax64(k, dpp_shift64<0x118>(k));  // row_shr:8
  k = kmax64(k, dpp_shift64<0x142>(k));  // row_bcast:15
  k = kmax64(k, dpp_shift64<0x143>(k));  // row_bcast:31
  return k;
}

__device__ inline unsigned sortable_f32(float f) {
  unsigned b = __float_as_uint(f);
  unsigned m = (unsigned)((int)b >> 31) | 0x80000000u;
  return b ^ m;  // u32 compare == float total order
}

__device__ inline unsigned med3u(unsigned a, unsigned b, unsigned c) {
  unsigned r;
  asm("v_med3_u32 %0, %1, %2, %3" : "=v"(r) : "v"(a), "v"(b), "v"(c));
  return r;
}

// sorted ascending insert of v into kk[24], dropping old max.
// All 24 med3 independent (desc order reads originals). v >= kk[23] -> no-op.
__device__ inline void ins24(unsigned kk[KNN], unsigned v) {
#pragma unroll
  for (int e = KNN - 1; e >= 1; --e) kk[e] = med3u(kk[e - 1], kk[e], v);
  kk[0] = kk[0] < v ? kk[0] : v;
}

// ---------------- tables ----------------
__global__ void init_tables(float* __restrict__ de, int* __restrict__ mp) {
  const int outs[5] = {64, 128, 256, 512, 1024};
  const int fds[5]  = {11, 22, 43, 86, 171};
  const int deo[5]  = {0, 11, 33, 76, 162};
  const int mpo[5]  = {0, 64, 192, 448, 960};
  const int tid = threadIdx.x;
  for (int c = 0; c < 5; ++c) {
    const int fd = fds[c], out = outs[c];
    for (int j = tid; j < fd; j += blockDim.x)
      de[deo[c] + j] = (float)pow(1000.0, (double)j / (double)fd);
    const double step = (double)(6 * fd - 1) / (double)(out - 1);
    for (int f = tid; f < out; f += blockDim.x)
      mp[mpo[c] + f] = (int)(step * (double)f);
  }
}

// ---------------- initial SPE embedding ----------------
__global__ __launch_bounds__(256) void embed_init(const float* __restrict__ xyz,
                                                  float* __restrict__ feat,
                                                  const float* __restrict__ de,
                                                  const int* __restrict__ mp) {
  int g = blockIdx.x * blockDim.x + threadIdx.x;
  if (g >= BATCH * NPTS0 * 64) return;
  int c = g & 63;
  int bn = g >> 6;
  int m = mp[c];
  int sc = m & 1;
  int a = m >> 1;
  int ci = a / 11;
  int j = a - ci * 11;
  float x = xyz[bn * 3 + ci];
  float ang = (100.0f * x) / de[j];
  feat[g] = sc ? cosf(ang) : sinf(ang);
}

// ---------------- FPS: 256 threads, DPP reduce, 1 barrier/iter ----------------
template <int PTS>
__device__ void fps_stage(const float* lds_cur, float* lds_next,
                          int* __restrict__ fps_idx, float* __restrict__ xyz_next,
                          uint64_t* red) {
  const int S = PTS * 128;
  const int tid = threadIdx.x;
  __syncthreads();
  float px[PTS], py[PTS], pz[PTS], dist[PTS];
  const unsigned nl = ~(unsigned)tid;
#pragma unroll
  for (int p = 0; p < PTS; ++p) {
    int gi = tid + p * 256;
    px[p] = lds_cur[3 * gi];
    py[p] = lds_cur[3 * gi + 1];
    pz[p] = lds_cur[3 * gi + 2];
    dist[p] = 1e10f;
  }
  unsigned sel = 0;
  if (tid == 0) {
    fps_idx[0] = 0;
    float a = lds_cur[0], b = lds_cur[1], c = lds_cur[2];
    xyz_next[0] = a; xyz_next[1] = b; xyz_next[2] = c;
    lds_next[0] = a; lds_next[1] = b; lds_next[2] = c;
  }
  for (int t = 1; t < S; ++t) {
    float cx = lds_cur[3 * sel], cy = lds_cur[3 * sel + 1], cz = lds_cur[3 * sel + 2];
    uint64_t kb = 0;
#pragma unroll
    for (int p = 0; p < PTS; ++p) {
      float dx = px[p] - cx, dy = py[p] - cy, dz = pz[p] - cz;
      float dd = dx * dx + dy * dy;
      dd = dd + dz * dz;
      float nd = fminf(dist[p], dd);
      dist[p] = nd;
      uint64_t key = ((uint64_t)__float_as_uint(nd) << 32) | (unsigned)(nl - (unsigned)(p * 256));
      kb = kmax64(kb, key);
    }
    kb = wave_reduce_max64(kb);
    if ((tid & 63) == 63) red[(t & 1) * 4 + (tid >> 6)] = kb;
    __syncthreads();
    uint64_t k0 = red[(t & 1) * 4 + 0], k1 = red[(t & 1) * 4 + 1];
    uint64_t k2 = red[(t & 1) * 4 + 2], k3 = red[(t & 1) * 4 + 3];
    uint64_t km = kmax64(kmax64(k0, k1), kmax64(k2, k3));
    sel = ~(unsigned)km;
    if (tid == 0) {
      fps_idx[t] = (int)sel;
      float a = lds_cur[3 * sel], b = lds_cur[3 * sel + 1], c = lds_cur[3 * sel + 2];
      xyz_next[3 * t] = a; xyz_next[3 * t + 1] = b; xyz_next[3 * t + 2] = c;
      lds_next[3 * t] = a; lds_next[3 * t + 1] = b; lds_next[3 * t + 2] = c;
    }
  }
}

__global__ __launch_bounds__(256) void fps_all(const float* __restrict__ xyz0,
                                               float* __restrict__ xyz1, float* __restrict__ xyz2,
                                               float* __restrict__ xyz3, float* __restrict__ xyz4,
                                               int* __restrict__ i0, int* __restrict__ i1,
                                               int* __restrict__ i2, int* __restrict__ i3) {
  __shared__ float lds[3 * (2048 + 1024 + 512 + 256 + 128)];
  __shared__ uint64_t red[8];
  const int b = blockIdx.x;
  float* l0 = lds;
  float* l1 = l0 + 3 * 2048;
  float* l2 = l1 + 3 * 1024;
  float* l3 = l2 + 3 * 512;
  float* l4 = l3 + 3 * 256;
  for (int t = threadIdx.x; t < 3 * 2048; t += 256) l0[t] = xyz0[(size_t)b * 3 * 2048 + t];
  fps_stage<8>(l0, l1, i0 + b * 1024, xyz1 + (size_t)b * 1024 * 3, red);
  fps_stage<4>(l1, l2, i1 + b * 512, xyz2 + (size_t)b * 512 * 3, red);
  fps_stage<2>(l2, l3, i2 + b * 256, xyz3 + (size_t)b * 256 * 3, red);
  fps_stage<1>(l3, l4, i3 + b * 128, xyz4 + (size_t)b * 128 * 3, red);
}

// ---------------- kNN phase 1: tau = 24th-smallest distance (value-only, med3 ladder) ----------
// block: 256 thr = 4 waves; lanes = 64 queries; each wave scans Np/4 candidates; merge; write tau.
static constexpr int MGS = 29;  // merge row stride (odd words -> conflict-free)
__global__ __launch_bounds__(256) void knn_tau(const float* __restrict__ db_xyz,
                                               const float* __restrict__ q_xyz,
                                               unsigned* __restrict__ tau,
                                               int Np, int S) {
  extern __shared__ float smem[];
  float4* db = (float4*)smem;                       // [Np]
  unsigned* mg = (unsigned*)(db + Np);              // [4][64][MGS]
  const int tid = threadIdx.x, lane = tid & 63, wv = tid >> 6;
  const int bpb = S >> 6;
  const int b = blockIdx.x / bpb;
  const int qbase = (blockIdx.x % bpb) * 64;
  for (int j = tid; j < Np; j += 256) {
    float x = db_xyz[((size_t)b * Np + j) * 3 + 0];
    float y = db_xyz[((size_t)b * Np + j) * 3 + 1];
    float z = db_xyz[((size_t)b * Np + j) * 3 + 2];
    float pn = x * x + y * y;
    pn = pn + z * z;                                // matches jnp.sum(xyz**2,-1)
    db[j] = make_float4(x, y, z, pn);
  }
  __syncthreads();
  const int s = qbase + lane;
  float qx = q_xyz[((size_t)b * S + s) * 3 + 0];
  float qy = q_xyz[((size_t)b * S + s) * 3 + 1];
  float qz = q_xyz[((size_t)b * S + s) * 3 + 2];
  float qn = qx * qx + qy * qy;
  qn = qn + qz * qz;
  unsigned kk[KNN];
#pragma unroll
  for (int e = 0; e < KNN; ++e) kk[e] = 0xFFFFFFFFu;
  const int cpw = Np >> 2;
  const int beg = wv * cpw, end = beg + cpw;
  for (int j0 = beg; j0 < end; j0 += 8) {
    float4 p[8];
#pragma unroll
    for (int u = 0; u < 8; ++u) p[u] = db[j0 + u];   // broadcast reads, prefetched
#pragma unroll
    for (int u = 0; u < 8; ++u) {
      float dot = fmaf(qz, p[u].z, fmaf(qy, p[u].y, qx * p[u].x));
      float d = (qn + p[u].w) - 2.0f * dot;
      unsigned su = sortable_f32(d);
      if (__any(su < kk[KNN - 1])) ins24(kk, su);    // med3 no-op for non-passing lanes
    }
  }
  unsigned* myrow = mg + (wv * 64 + lane) * MGS;
#pragma unroll
  for (int e = 0; e < KNN; ++e) myrow[e] = kk[e];
  __syncthreads();
  if (wv == 0) {
    for (int w = 1; w < 4; ++w) {
      const unsigned* orow = mg + (w * 64 + lane) * MGS;
#pragma unroll
      for (int e = 0; e < KNN; ++e) {
        unsigned v = orow[e];
        if (__any(v < kk[KNN - 1])) ins24(kk, v);
      }
    }
    tau[(size_t)b * S + s] = kk[KNN - 1];
  }
}

// ---------------- kNN phase 2: collect + exact tie handling + sort ----------------
// one wave per query; lanes sweep candidates; ballot-compaction; bitonic sort of d<tau set.
__global__ __launch_bounds__(256) void knn_collect(const float* __restrict__ db_xyz,
                                                   const float* __restrict__ q_xyz,
                                                   const unsigned* __restrict__ tau,
                                                   int* __restrict__ out_idx,
                                                   int Np, int S) {
  __shared__ uint64_t bufA[4][24];  // d < tau (index order, <=23)
  __shared__ uint64_t bufB[4][24];  // d == tau (index order = tie order)
  const int lane = threadIdx.x & 63, wv = threadIdx.x >> 6;
  const int qi = blockIdx.x * 4 + wv;
  const int b = qi / S, s = qi % S;
  float qx = q_xyz[((size_t)b * S + s) * 3 + 0];
  float qy = q_xyz[((size_t)b * S + s) * 3 + 1];
  float qz = q_xyz[((size_t)b * S + s) * 3 + 2];
  float qn = qx * qx + qy * qy;
  qn = qn + qz * qz;
  const unsigned tt = tau[qi];
  int cntA = 0, cntB = 0;
  const unsigned long long lmlt = (1ull << lane) - 1;
  const int iters = Np >> 6;
  for (int it = 0; it < iters; ++it) {
    int j = it * 64 + lane;
    float x = db_xyz[((size_t)b * Np + j) * 3 + 0];
    float y = db_xyz[((size_t)b * Np + j) * 3 + 1];
    float z = db_xyz[((size_t)b * Np + j) * 3 + 2];
    float pn = x * x + y * y;
    pn = pn + z * z;
    float dot = fmaf(qz, z, fmaf(qy, y, qx * x));
    float d = (qn + pn) - 2.0f * dot;
    unsigned su = sortable_f32(d);
    unsigned long long mlt = __ballot(su < tt);
    unsigned long long meq = __ballot(su == tt);
    if (mlt) {
      int pos = cntA + __popcll(mlt & lmlt);
      if (su < tt && pos < 24) bufA[wv][pos] = ((uint64_t)su << 32) | (unsigned)j;
      cntA += __popcll(mlt);
    }
    if (meq) {
      int pos = cntB + __popcll(meq & lmlt);
      if (su == tt && pos < 24) bufB[wv][pos] = ((uint64_t)su << 32) | (unsigned)j;
      cntB += __popcll(meq);
    }
  }
  // bitonic sort (64 lanes) of the A set by (d, idx)
  uint64_t v = (lane < cntA) ? bufA[wv][lane] : ~0ull;
#pragma unroll
  for (int k = 2; k <= 64; k <<= 1) {
#pragma unroll
    for (int m = k >> 1; m > 0; m >>= 1) {
      uint64_t o = __shfl_xor(v, m);
      bool takemin = (((lane & k) == 0) == ((lane & m) == 0));
      uint64_t mn = v < o ? v : o;
      uint64_t mx = v < o ? o : v;
      v = takemin ? mn : mx;
    }
  }
  if (lane < KNN) {
    uint64_t key = (lane < cntA) ? v : bufB[wv][lane - cntA];
    out_idx[(size_t)qi * KNN + lane] = (int)(unsigned)key;
  }
}

// ---------------- gather feat_s ----------------
__global__ __launch_bounds__(256) void gather_feat_s(const float* __restrict__ feat,
                                                     const int* __restrict__ fidx,
                                                     float* __restrict__ out, int Np, int S, int C) {
  int g = blockIdx.x * blockDim.x + threadIdx.x;
  if (g >= BATCH * S * C) return;
  int c = g % C;
  int bs = g / C;
  int s = bs % S;
  int b = bs / S;
  int src = fidx[b * S + s];
  out[g] = feat[((size_t)b * Np + src) * C + c];
}

// ---------------- global std sums (xyz_c and feat_c), f64 ----------------
__global__ __launch_bounds__(256) void center_reduce(const float* __restrict__ xyz,
                                                     const float* __restrict__ xyz_s,
                                                     const float* __restrict__ feat,
                                                     const float* __restrict__ feat_s,
                                                     const int* __restrict__ kidx,
                                                     double* __restrict__ sums,
                                                     int Np, int S, int C) {
  int g = blockIdx.x * blockDim.x + threadIdx.x;
  int total = BATCH * S * KNN;
  double sx = 0, sxx = 0, sf = 0, sff = 0;
  if (g < total) {
    int bs = g / KNN;
    int s = bs % S;
    int b = bs / S;
    int j = kidx[g];
    const float* pc = xyz + ((size_t)b * Np + j) * 3;
    const float* qc = xyz_s + ((size_t)b * S + s) * 3;
    for (int c = 0; c < 3; ++c) {
      float v = pc[c] - qc[c];
      sx += (double)v;
      sxx += (double)v * (double)v;
    }
    const float4* fr = (const float4*)(feat + ((size_t)b * Np + j) * C);
    const float4* fs = (const float4*)(feat_s + ((size_t)b * S + s) * C);
    for (int c = 0; c < C / 4; ++c) {
      float4 a = fr[c], bq = fs[c];
      float v0 = a.x - bq.x, v1 = a.y - bq.y, v2 = a.z - bq.z, v3 = a.w - bq.w;
      sf += (double)v0 + (double)v1 + (double)v2 + (double)v3;
      sff += (double)v0 * v0 + (double)v1 * v1 + (double)v2 * v2 + (double)v3 * v3;
    }
  }
#pragma unroll
  for (int m = 1; m < 64; m <<= 1) {
    sx += __shfl_xor(sx, m);
    sxx += __shfl_xor(sxx, m);
    sf += __shfl_xor(sf, m);
    sff += __shfl_xor(sff, m);
  }
  __shared__ double part[4][4];
  int wv = threadIdx.x >> 6;
  if ((threadIdx.x & 63) == 0) { part[wv][0] = sx; part[wv][1] = sxx; part[wv][2] = sf; part[wv][3] = sff; }
  __syncthreads();
  if (threadIdx.x == 0) {
    double a = 0, b2 = 0, c2 = 0, d2 = 0;
    for (int w = 0; w < 4; ++w) { a += part[w][0]; b2 += part[w][1]; c2 += part[w][2]; d2 += part[w][3]; }
    atomicAdd(&sums[0], a);
    atomicAdd(&sums[1], b2);
    atomicAdd(&sums[2], c2);
    atomicAdd(&sums[3], d2);
  }
}

// ---------------- aggregation: wave per query, per-lane direct trig ----------------
template <int CH>
__global__ __launch_bounds__(256) void agg_kernel(const float* __restrict__ xyz,
                                                  const float* __restrict__ xyz_s,
                                                  const float* __restrict__ feat,
                                                  const float* __restrict__ feat_s,
                                                  const int* __restrict__ kidx,
                                                  const double* __restrict__ csums,
                                                  const float* __restrict__ de,
                                                  const int* __restrict__ mp,
                                                  float* __restrict__ agg,
                                                  int Np, int S, int C, int fd,
                                                  double nx_d, double nf_d) {
  const int lane = threadIdx.x & 63;
  const int wv = threadIdx.x >> 6;
  const int q = blockIdx.x * 4 + wv;
  const int s = q % S;
  const int b = q / S;
  double sxd = csums[0], sxxd = csums[1], sfd = csums[2], sffd = csums[3];
  float stdx = sqrtf((float)((sxxd - sxd * sxd / nx_d) / (nx_d - 1.0)));
  float stdf = sqrtf((float)((sffd - sfd * sfd / nf_d) / (nf_d - 1.0)));
  float invx = 1.0f / (stdx + 1e-5f);
  float invf = 1.0f / (stdf + 1e-5f);
  float cx = xyz_s[((size_t)b * S + s) * 3 + 0];
  float cy = xyz_s[((size_t)b * S + s) * 3 + 1];
  float cz = xyz_s[((size_t)b * S + s) * 3 + 2];
  const float* fsrow = feat_s + ((size_t)b * S + s) * C;
  int ci[CH];
  float dev[CH], fsv[CH];
  bool issin[CH], fh[CH];
#pragma unroll
  for (int ch = 0; ch < CH; ++ch) {
    int f = ch * 64 + lane;
    int m = mp[f];
    issin[ch] = (m & 1) == 0;
    int a = m >> 1;
    int cc = a / fd;
    ci[ch] = cc;
    dev[ch] = de[a - cc * fd];
    fh[ch] = f < C;
    fsv[ch] = fh[ch] ? fsrow[f] : fsrow[f - C];
  }
  float wmax[CH], wsum[CH];
#pragma unroll
  for (int ch = 0; ch < CH; ++ch) { wmax[ch] = -3.4e38f; wsum[ch] = 0.f; }
  const int* krow = kidx + ((size_t)b * S + s) * KNN;
  for (int k = 0; k < KNN; ++k) {
    int j = krow[k];
    const float* pr = xyz + ((size_t)b * Np + j) * 3;
    float n0 = (pr[0] - cx) * invx;
    float n1 = (pr[1] - cy) * invx;
    float n2 = (pr[2] - cz) * invx;
    const float* fr = feat + ((size_t)b * Np + j) * C;
#pragma unroll
    for (int ch = 0; ch < CH; ++ch) {
      float xv = (ci[ch] == 0) ? n0 : ((ci[ch] == 1) ? n1 : n2);
      float ang = (100.0f * xv) / dev[ch];
      float sv, cv;
      sincosf(ang, &sv, &cv);
      float pef = issin[ch] ? sv : cv;
      int f = ch * 64 + lane;
      float val = fh[ch] ? (fr[f] - fsv[ch]) * invf : fsv[ch];
      float w = (val + pef) * pef;
      wmax[ch] = fmaxf(wmax[ch], w);
      wsum[ch] += w;
    }
  }
  float* arow = agg + (size_t)q * (CH * 64);
#pragma unroll
  for (int ch = 0; ch < CH; ++ch) {
    int f = ch * 64 + lane;
    arow[f] = wmax[ch] + wsum[ch] / (float)KNN;
  }
}

// ---------------- BatchNorm reduce ----------------
__global__ __launch_bounds__(256) void bn_reduce(const float* __restrict__ agg,
                                                 double* __restrict__ bns,
                                                 int R, int D) {
  int r0 = blockIdx.x * 64;
  for (int c = threadIdx.x; c < D; c += 256) {
    double s = 0, ss = 0;
    for (int r = 0; r < 64; ++r) {
      float v = agg[(size_t)(r0 + r) * D + c];
      s += (double)v;
      ss += (double)v * (double)v;
    }
    atomicAdd(&bns[c], s);
    atomicAdd(&bns[D + c], ss);
  }
}

// ---------------- BatchNorm apply + exact GELU ----------------
__global__ __launch_bounds__(256) void bn_apply(const float* __restrict__ agg,
                                                const double* __restrict__ bns,
                                                const float* __restrict__ gamma,
                                                const float* __restrict__ beta,
                                                float* __restrict__ outf, int R, int D) {
  int g = blockIdx.x * blockDim.x + threadIdx.x;
  if (g >= R * D) return;
  int c = g % D;
  double n = (double)R;
  double mu = bns[c] / n;
  double var = bns[D + c] / n - mu * mu;  // biased
  float mean = (float)mu;
  float rstd = 1.0f / sqrtf((float)var + 1e-5f);
  float x = (agg[g] - mean) * rstd;
  float y = gamma[c] * x + beta[c];
  float e = erff(y * 0.70710678118654752440f);
  outf[g] = 0.5f * y * (1.0f + e);
}

// ---------------- final: max + mean over S=128 ----------------
__global__ __launch_bounds__(256) void final_kernel(const float* __restrict__ feat,
                                                    float* __restrict__ out) {
  int g = blockIdx.x * blockDim.x + threadIdx.x;
  if (g >= BATCH * 1024) return;
  int f = g % 1024;
  int b = g / 1024;
  const float* base = feat + (size_t)b * 128 * 1024 + f;
  float mx = -3.4e38f;
  float sm = 0.f;
  for (int s = 0; s < 128; ++s) {
    float v = base[(size_t)s * 1024];
    mx = fmaxf(mx, v);
    sm += v;
  }
  out[g] = mx + sm / 128.0f;
}

// ---------------- host ----------------
extern "C" void kernel_launch(void* const* d_in, const int* in_sizes, int n_in,
                              void* d_out, int out_size, void* d_ws, size_t ws_size,
                              hipStream_t stream) {
  (void)in_sizes; (void)n_in; (void)out_size;
  if (ws_size < WS_NEED) return;
  const float* xyz = (const float*)d_in[0];
  const float* gam[4] = {(const float*)d_in[1], (const float*)d_in[3], (const float*)d_in[5], (const float*)d_in[7]};
  const float* bet[4] = {(const float*)d_in[2], (const float*)d_in[4], (const float*)d_in[6], (const float*)d_in[8]};
  char* ws = (char*)d_ws;
  double* stats = (double*)(ws + OFF_STATS);
  double* bns = (double*)(ws + OFF_BN);
  float* de = (float*)(ws + OFF_DE);
  int* mp = (int*)(ws + OFF_MAP);
  float* xyz1 = (float*)(ws + OFF_XYZ1);
  float* xyz2 = (float*)(ws + OFF_XYZ2);
  float* xyz3 = (float*)(ws + OFF_XYZ3);
  float* xyz4 = (float*)(ws + OFF_XYZ4);
  int* fpsI[4] = {(int*)(ws + OFF_FPS0), (int*)(ws + OFF_FPS1), (int*)(ws + OFF_FPS2), (int*)(ws + OFF_FPS3)};
  int* kidx = (int*)(ws + OFF_KNN);
  float* feata = (float*)(ws + OFF_FEATA);
  float* featb = (float*)(ws + OFF_FEATB);
  float* feats = (float*)(ws + OFF_FEATS);
  unsigned* tau = (unsigned*)(ws + OFF_FEATS);  // dead once gather_feat_s writes feats
  float* agg = (float*)(ws + OFF_AGG);

  hipMemsetAsync(ws, 0, 32768, stream);
  init_tables<<<1, 256, 0, stream>>>(de, mp);
  fps_all<<<16, 256, 0, stream>>>(xyz, xyz1, xyz2, xyz3, xyz4, fpsI[0], fpsI[1], fpsI[2], fpsI[3]);
  embed_init<<<(BATCH * NPTS0 * 64) / 256, 256, 0, stream>>>(xyz, feata, de, mp);

  const int Ns[4] = {2048, 1024, 512, 256};
  const int Cs[4] = {64, 128, 256, 512};
  const int fdv[4] = {22, 43, 86, 171};
  const int deo[4] = {11, 33, 76, 162};
  const int mpo[4] = {64, 192, 448, 960};
  const float* xin[5] = {xyz, xyz1, xyz2, xyz3, xyz4};
  float* fcur = feata;
  float* fnext = featb;
  int bnoff = 0;
  for (int i = 0; i < 4; ++i) {
    const int Np = Ns[i], S = Np / 2, C = Cs[i], D = 2 * C;
    size_t tau_lds = (size_t)Np * 16 + (size_t)4 * 64 * MGS * 4;
    knn_tau<<<16 * (S / 64), 256, tau_lds, stream>>>(xin[i], xin[i + 1], tau, Np, S);
    knn_collect<<<(BATCH * S) / 4, 256, 0, stream>>>(xin[i], xin[i + 1], tau, kidx, Np, S);
    gather_feat_s<<<(BATCH * S * C) / 256, 256, 0, stream>>>(fcur, fpsI[i], feats, Np, S, C);
    const int tuples = BATCH * S * KNN;
    center_reduce<<<(tuples + 255) / 256, 256, 0, stream>>>(xin[i], xin[i + 1], fcur, feats, kidx,
                                                            stats + 4 * i, Np, S, C);
    double nx = (double)tuples * 3.0;
    double nf = (double)tuples * (double)C;
    dim3 ag((BATCH * S) / 4);
    switch (D / 64) {
      case 2:
        agg_kernel<2><<<ag, 256, 0, stream>>>(xin[i], xin[i + 1], fcur, feats, kidx, stats + 4 * i,
                                              de + deo[i], mp + mpo[i], agg, Np, S, C, fdv[i], nx, nf);
        break;
      case 4:
        agg_kernel<4><<<ag, 256, 0, stream>>>(xin[i], xin[i + 1], fcur, feats, kidx, stats + 4 * i,
                                              de + deo[i], mp + mpo[i], agg, Np, S, C, fdv[i], nx, nf);
        break;
      case 8:
        agg_kernel<8><<<ag, 256, 0, stream>>>(xin[i], xin[i + 1], fcur, feats, kidx, stats + 4 * i,
                                              de + deo[i], mp + mpo[i], agg, Np, S, C, fdv[i], nx, nf);
        break;
      default:
        agg_kernel<16><<<ag, 256, 0, stream>>>(xin[i], xin[i + 1], fcur, feats, kidx, stats + 4 * i,
                                               de + deo[i], mp + mpo[i], agg, Np, S, C, fdv[i], nx, nf);
        break;
    }
    const int R = BATCH * S;
    bn_reduce<<<R / 64, 256, 0, stream>>>(agg, bns + bnoff, R, D);
    bn_apply<<<(R * D) / 256, 256, 0, stream>>>(agg, bns + bnoff, gam[i], bet[i], fnext, R, D);
    bnoff += 2 * D;
    float* t = fcur; fcur = fnext; fnext = t;
  }
  final_kernel<<<(BATCH * 1024) / 256, 256, 0, stream>>>(fcur, (float*)d_out);
}